// Round 10
// baseline (394.451 us; speedup 1.0000x reference)
//
#include <hip/hip_runtime.h>

// BiPixelMambaLayer: D_MODEL=256, D_INNER=512, D_STATE=16, D_CONV=4, DT_RANK=16, PATCH=64
// x: (2, 256, 4096) fp32.  Mamba batch B'=128 (= 2*64), seq NPT=64, channels along patch axis.
//
// Workspace layout (float slots), total ~85.8 MB:
//   XZ  [128][64][1024]       = 8388608
//   XC  [128][64][512]        = 4194304
//   DL  [128][64][512]        = 4194304
//   BCB [128][64][32]         = 262144   (first half doubles as in_proj W bf16 during K1)
//   YF  bf16 [128][64][512]   = 2097152 float-slots
//   YB  bf16 [128][64][512]   = 2097152 float-slots
//   WOB bf16 [256][512]       = 65536 float-slots
//   WX  bf16 [544][512]       = 139264 float-slots (fused [Wd; W6[16:48]] per branch)

#define OFF_XZ 0
#define OFF_XC 8388608
#define OFF_DL 12582912
#define OFF_BC 16777216
#define OFF_YF 17039360
#define OFF_YB 19136512
#define OFF_WOB 21233664
#define OFF_WX 21299200

typedef __attribute__((ext_vector_type(8))) short short8;
typedef __attribute__((ext_vector_type(4))) float f32x4;

__device__ __forceinline__ float siluf(float v) {
    return v / (1.f + __expf(-v));
}
__device__ __forceinline__ float softplusf(float v) {
    return (v > 20.f) ? v : log1pf(__expf(v));
}
__device__ __forceinline__ unsigned short f2bf(float f) {
    union { float f; unsigned int u; } v; v.f = f;
    unsigned int u = v.u;
    return (unsigned short)((u + 0x7FFFu + ((u >> 16) & 1u)) >> 16);
}

// ---------------- K0: fp32 -> bf16 weight convert (generic) ----------------
__global__ __launch_bounds__(256) void k_cvt_w(
    const float* __restrict__ W, unsigned short* __restrict__ Wb, int n4)
{
    int i = blockIdx.x * 256 + threadIdx.x;
    if (i >= n4) return;
    float4 v = *(const float4*)(W + i * 4);
    ushort4 o;
    o.x = f2bf(v.x); o.y = f2bf(v.y); o.z = f2bf(v.z); o.w = f2bf(v.w);
    *(ushort4*)(Wb + i * 4) = o;
}

// ---------------- K0b: build Wx = [dtp_w @ W6[:16] ; W6[16:48]] in bf16 ----------------
__global__ __launch_bounds__(256) void k_mk_wx(
    const float* __restrict__ W6, const float* __restrict__ dtw,
    unsigned short* __restrict__ Wx)
{
    const int n = blockIdx.x;          // 0..543
    const int c = threadIdx.x;         // handles c and c+256
    if (n < 512) {
        float a0 = 0.f, a1 = 0.f;
        #pragma unroll
        for (int r = 0; r < 16; ++r) {
            float w = dtw[n * 16 + r];
            a0 = fmaf(w, W6[r * 512 + c], a0);
            a1 = fmaf(w, W6[r * 512 + c + 256], a1);
        }
        Wx[n * 512 + c] = f2bf(a0);
        Wx[n * 512 + c + 256] = f2bf(a1);
    } else {
        int rr = n - 496;              // W6 rows 16..47 (B then C)
        Wx[n * 512 + c] = f2bf(W6[rr * 512 + c]);
        Wx[n * 512 + c + 256] = f2bf(W6[rr * 512 + c + 256]);
    }
}

// ---------------- K1: LayerNorm + in_proj (256 -> 1024) via bf16 MFMA ----------------
__global__ __launch_bounds__(256) void k_ln_inproj_mfma(
    const float* __restrict__ x, const float* __restrict__ g,
    const float* __restrict__ bt, const unsigned short* __restrict__ Wb,
    float* __restrict__ xz)
{
    __shared__ unsigned short sxb[64 * 256];   // 32 KB, bf16, XOR-swizzled rows of 512B
    const int bid = blockIdx.x;
    const int pg = bid >> 2, og = bid & 3;
    const int p0 = pg * 64;
    const int tid = threadIdx.x;
    const int wave = tid >> 6, lane = tid & 63;
    const int b = pg >> 6, pp = pg & 63;
    const float* xb = x + ((size_t)b * 256) * 4096 + pp;

    const int c = lane * 4;
    const float g0 = g[c + 0], g1 = g[c + 1], g2 = g[c + 2], g3 = g[c + 3];
    const float b0 = bt[c + 0], b1 = bt[c + 1], b2 = bt[c + 2], b3 = bt[c + 3];
    for (int i = 0; i < 16; ++i) {
        int m = wave * 16 + i;
        const float* xr = xb + m * 64;
        float v0 = xr[(size_t)(c + 0) * 4096];
        float v1 = xr[(size_t)(c + 1) * 4096];
        float v2 = xr[(size_t)(c + 2) * 4096];
        float v3 = xr[(size_t)(c + 3) * 4096];
        float s = v0 + v1 + v2 + v3;
        #pragma unroll
        for (int o = 32; o; o >>= 1) s += __shfl_xor(s, o);
        float mu = s * (1.f / 256.f);
        float q0 = v0 - mu, q1 = v1 - mu, q2 = v2 - mu, q3 = v3 - mu;
        float q = q0 * q0 + q1 * q1 + q2 * q2 + q3 * q3;
        #pragma unroll
        for (int o = 32; o; o >>= 1) q += __shfl_xor(q, o);
        float rs = rsqrtf(q * (1.f / 256.f) + 1e-5f);
        ushort4 pk;
        pk.x = f2bf(q0 * rs * g0 + b0);
        pk.y = f2bf(q1 * rs * g1 + b1);
        pk.z = f2bf(q2 * rs * g2 + b2);
        pk.w = f2bf(q3 * rs * g3 + b3);
        int byte = m * 512 + lane * 8;
        byte ^= (m & 7) << 4;
        *(ushort4*)((char*)sxb + byte) = pk;
    }
    __syncthreads();

    const int nbase = og * 256 + wave * 64;
    const int l15 = lane & 15, lg = lane >> 4;
    f32x4 acc[4][4];
    #pragma unroll
    for (int mi = 0; mi < 4; ++mi)
        #pragma unroll
        for (int ni = 0; ni < 4; ++ni) acc[mi][ni] = (f32x4){0.f, 0.f, 0.f, 0.f};

    const unsigned short* wrow[4];
    #pragma unroll
    for (int ni = 0; ni < 4; ++ni)
        wrow[ni] = Wb + (size_t)(nbase + ni * 16 + l15) * 256 + lg * 8;

    #pragma unroll 2
    for (int k0 = 0; k0 < 256; k0 += 32) {
        short8 a[4], bfr[4];
        #pragma unroll
        for (int mi = 0; mi < 4; ++mi) {
            int row = mi * 16 + l15;
            int byte = row * 512 + k0 * 2 + lg * 16;
            byte ^= (row & 7) << 4;
            a[mi] = *(const short8*)((const char*)sxb + byte);
        }
        #pragma unroll
        for (int ni = 0; ni < 4; ++ni)
            bfr[ni] = *(const short8*)(wrow[ni] + k0);
        #pragma unroll
        for (int mi = 0; mi < 4; ++mi)
            #pragma unroll
            for (int ni = 0; ni < 4; ++ni)
                acc[mi][ni] = __builtin_amdgcn_mfma_f32_16x16x32_bf16(
                    a[mi], bfr[ni], acc[mi][ni], 0, 0, 0);
    }

    #pragma unroll
    for (int mi = 0; mi < 4; ++mi)
        #pragma unroll
        for (int ni = 0; ni < 4; ++ni)
            #pragma unroll
            for (int r = 0; r < 4; ++r)
                xz[(size_t)(p0 + mi * 16 + lg * 4 + r) * 1024 + nbase + ni * 16 + l15] =
                    acc[mi][ni][r];
}

// ---------------- K2: fused conv+SiLU -> GEMM [64x512]@Wx^T -> delta/B/C ----------------
// Grid 256 = 128 bp x 2 og (column halves of 272). Block 256 = 4 waves.
// Wave w: conv for positions w*16..w*16+15 into LDS (bf16, swizzled), then MFMA
// M-tile rows w*16.., 17 N-tiles of this og half. Epilogue: softplus(+dtb) for
// cols<512 -> delta; raw cols 512..543 -> bcb.
__global__ __launch_bounds__(256) void k_cxg(
    const float* __restrict__ xz, const float* __restrict__ cw,
    const float* __restrict__ cb, const unsigned short* __restrict__ Wx,
    const float* __restrict__ dtb,
    float* __restrict__ xc, float* __restrict__ delta,
    float* __restrict__ bcb, int rev)
{
    __shared__ unsigned short sxb[64 * 512];   // 64 KB, rows of 1024B, XOR-swizzled
    const int blk = blockIdx.x;
    const int bp = blk >> 1, og = blk & 1;
    const int tid = threadIdx.x;
    const int wave = tid >> 6, lane = tid & 63;
    const size_t xzrow = (size_t)bp * 64;
    const int m0 = wave * 16;

    // ---- conv + silu: lane owns channels {ga = lane*4..+3} and {gb = 256+lane*4..+3} ----
    {
        const int da = lane * 4, db = 256 + lane * 4;
        float4 wa0 = *(const float4*)&cw[(da + 0) * 4];
        float4 wa1 = *(const float4*)&cw[(da + 1) * 4];
        float4 wa2 = *(const float4*)&cw[(da + 2) * 4];
        float4 wa3 = *(const float4*)&cw[(da + 3) * 4];
        float4 wb0 = *(const float4*)&cw[(db + 0) * 4];
        float4 wb1 = *(const float4*)&cw[(db + 1) * 4];
        float4 wb2 = *(const float4*)&cw[(db + 2) * 4];
        float4 wb3 = *(const float4*)&cw[(db + 3) * 4];
        float4 ba = *(const float4*)&cb[da];
        float4 bb = *(const float4*)&cb[db];

        float4 a1 = {0,0,0,0}, a2 = {0,0,0,0}, a3 = {0,0,0,0};
        float4 c1 = {0,0,0,0}, c2 = {0,0,0,0}, c3 = {0,0,0,0};
        if (m0 > 0) {
            int i1 = m0 - 1, i2 = m0 - 2, i3 = m0 - 3;
            int l1 = rev ? 63 - i1 : i1, l2 = rev ? 63 - i2 : i2, l3 = rev ? 63 - i3 : i3;
            a1 = *(const float4*)&xz[(xzrow + l1) * 1024 + da];
            a2 = *(const float4*)&xz[(xzrow + l2) * 1024 + da];
            a3 = *(const float4*)&xz[(xzrow + l3) * 1024 + da];
            c1 = *(const float4*)&xz[(xzrow + l1) * 1024 + db];
            c2 = *(const float4*)&xz[(xzrow + l2) * 1024 + db];
            c3 = *(const float4*)&xz[(xzrow + l3) * 1024 + db];
        }
        for (int p = 0; p < 16; ++p) {
            int i = m0 + p;
            int l = rev ? 63 - i : i;
            float4 cura = *(const float4*)&xz[(xzrow + l) * 1024 + da];
            float4 curb = *(const float4*)&xz[(xzrow + l) * 1024 + db];
            float4 sa, sb;
            sa.x = siluf(wa0.w * cura.x + wa0.z * a1.x + wa0.y * a2.x + wa0.x * a3.x + ba.x);
            sa.y = siluf(wa1.w * cura.y + wa1.z * a1.y + wa1.y * a2.y + wa1.x * a3.y + ba.y);
            sa.z = siluf(wa2.w * cura.z + wa2.z * a1.z + wa2.y * a2.z + wa2.x * a3.z + ba.z);
            sa.w = siluf(wa3.w * cura.w + wa3.z * a1.w + wa3.y * a2.w + wa3.x * a3.w + ba.w);
            sb.x = siluf(wb0.w * curb.x + wb0.z * c1.x + wb0.y * c2.x + wb0.x * c3.x + bb.x);
            sb.y = siluf(wb1.w * curb.y + wb1.z * c1.y + wb1.y * c2.y + wb1.x * c3.y + bb.y);
            sb.z = siluf(wb2.w * curb.z + wb2.z * c1.z + wb2.y * c2.z + wb2.x * c3.z + bb.z);
            sb.w = siluf(wb3.w * curb.w + wb3.z * c1.w + wb3.y * c2.w + wb3.x * c3.w + bb.w);
            if (og == 0) {
                *(float4*)&xc[(xzrow + i) * 512 + da] = sa;
                *(float4*)&xc[(xzrow + i) * 512 + db] = sb;
            }
            ushort4 pa, pb;
            pa.x = f2bf(sa.x); pa.y = f2bf(sa.y); pa.z = f2bf(sa.z); pa.w = f2bf(sa.w);
            pb.x = f2bf(sb.x); pb.y = f2bf(sb.y); pb.z = f2bf(sb.z); pb.w = f2bf(sb.w);
            int bytea = i * 1024 + da * 2; bytea ^= (i & 7) << 4;
            int byteb = i * 1024 + db * 2; byteb ^= (i & 7) << 4;
            *(ushort4*)((char*)sxb + bytea) = pa;
            *(ushort4*)((char*)sxb + byteb) = pb;
            a3 = a2; a2 = a1; a1 = cura;
            c3 = c2; c2 = c1; c1 = curb;
        }
    }
    __syncthreads();

    // ---- GEMM: M-tile rows m0.., N = og*272 .. +271 (17 tiles), K = 512 ----
    const int l15 = lane & 15, lg = lane >> 4;
    f32x4 acc[17];
    #pragma unroll
    for (int ni = 0; ni < 17; ++ni) acc[ni] = (f32x4){0.f, 0.f, 0.f, 0.f};
    const unsigned short* bbase = Wx + (size_t)(og * 272 + l15) * 512 + lg * 8;
    const int arow = m0 + l15;
    const int abase = arow * 1024 + lg * 16;
    const int aswz = (arow & 7) << 4;

    for (int k0 = 0; k0 < 512; k0 += 32) {
        short8 af = *(const short8*)((const char*)sxb + ((abase + k0 * 2) ^ aswz));
        #pragma unroll
        for (int ni = 0; ni < 17; ++ni) {
            short8 bw = *(const short8*)(bbase + (size_t)ni * 8192 + k0);
            acc[ni] = __builtin_amdgcn_mfma_f32_16x16x32_bf16(af, bw, acc[ni], 0, 0, 0);
        }
    }

    // ---- epilogue ----
    #pragma unroll
    for (int ni = 0; ni < 17; ++ni) {
        int col = og * 272 + ni * 16 + l15;
        if (col < 512) {
            float bias = dtb[col];
            #pragma unroll
            for (int r = 0; r < 4; ++r) {
                int pos = m0 + lg * 4 + r;
                delta[(xzrow + pos) * 512 + col] = softplusf(acc[ni][r] + bias);
            }
        } else {
            #pragma unroll
            for (int r = 0; r < 4; ++r) {
                int pos = m0 + lg * 4 + r;
                bcb[(xzrow + pos) * 32 + (col - 512)] = acc[ni][r];
            }
        }
    }
}

// ---------------- K4: selective scan + D*u + SiLU(z) gate -> bf16 ----------------
__global__ __launch_bounds__(256) void k_scan(
    const float* __restrict__ delta, const float* __restrict__ u_,
    const float* __restrict__ bc_, const float* __restrict__ xz,
    const float* __restrict__ A_log, const float* __restrict__ Dp,
    unsigned short* __restrict__ yout, int rev)
{
    const int bid = blockIdx.x;
    const int bp  = bid >> 1;
    const int d   = ((bid & 1) << 8) + threadIdx.x;

    float a[16];
    #pragma unroll
    for (int n = 0; n < 16; ++n) a[n] = -__expf(A_log[(size_t)d * 16 + n]);
    const float Dd = Dp[d];

    float h[16];
    #pragma unroll
    for (int n = 0; n < 16; ++n) h[n] = 0.f;

    for (int l = 0; l < 64; ++l) {
        size_t base = (size_t)bp * 64 + l;
        float dl = delta[base * 512 + d];
        float uu = u_[base * 512 + d];
        float du = dl * uu;
        const float4* bc = (const float4*)(bc_ + base * 32);
        float y = 0.f;
        #pragma unroll
        for (int n4 = 0; n4 < 4; ++n4) {
            float4 Bv = bc[n4];
            float4 Cv = bc[4 + n4];
            int n = n4 * 4;
            h[n + 0] = fmaf(__expf(dl * a[n + 0]), h[n + 0], du * Bv.x); y = fmaf(h[n + 0], Cv.x, y);
            h[n + 1] = fmaf(__expf(dl * a[n + 1]), h[n + 1], du * Bv.y); y = fmaf(h[n + 1], Cv.y, y);
            h[n + 2] = fmaf(__expf(dl * a[n + 2]), h[n + 2], du * Bv.z); y = fmaf(h[n + 2], Cv.z, y);
            h[n + 3] = fmaf(__expf(dl * a[n + 3]), h[n + 3], du * Bv.w); y = fmaf(h[n + 3], Cv.w, y);
        }
        y = fmaf(Dd, uu, y);
        int lo = rev ? 63 - l : l;
        float zv = xz[((size_t)bp * 64 + lo) * 1024 + 512 + d];
        yout[((size_t)bp * 64 + lo) * 512 + d] = f2bf(y * siluf(zv));
    }
}

// ---------------- K5: out_proj (512 -> 256) via bf16 MFMA + un-shuffle + residual -----
__global__ __launch_bounds__(256) void k_outproj_mfma(
    const unsigned short* __restrict__ yf, const unsigned short* __restrict__ yb,
    const unsigned short* __restrict__ wob, const float* __restrict__ x,
    float* __restrict__ out)
{
    __shared__ float sD[64][257];
    const int blk = blockIdx.x;
    const int g = blk >> 6, l = blk & 63;
    const int tid = threadIdx.x;
    const int wave = tid >> 6, lane = tid & 63;
    const int l15 = lane & 15, lg = lane >> 4;
    const int cbase = wave * 64;

    f32x4 acc[4][4];
    #pragma unroll
    for (int mi = 0; mi < 4; ++mi)
        #pragma unroll
        for (int ni = 0; ni < 4; ++ni) acc[mi][ni] = (f32x4){0.f, 0.f, 0.f, 0.f};

    const unsigned short* arf[4];
    const unsigned short* arb[4];
    #pragma unroll
    for (int mi = 0; mi < 4; ++mi) {
        size_t idx = (((size_t)(g * 64 + mi * 16 + l15)) * 64 + l) * 512 + lg * 8;
        arf[mi] = yf + idx;
        arb[mi] = yb + idx;
    }
    const unsigned short* brow[4];
    #pragma unroll
    for (int ni = 0; ni < 4; ++ni)
        brow[ni] = wob + (size_t)(cbase + ni * 16 + l15) * 512 + lg * 8;

    #pragma unroll 2
    for (int k0 = 0; k0 < 512; k0 += 32) {
        short8 bw[4], af[4], ab[4];
        #pragma unroll
        for (int ni = 0; ni < 4; ++ni) bw[ni] = *(const short8*)(brow[ni] + k0);
        #pragma unroll
        for (int mi = 0; mi < 4; ++mi) {
            af[mi] = *(const short8*)(arf[mi] + k0);
            ab[mi] = *(const short8*)(arb[mi] + k0);
        }
        #pragma unroll
        for (int mi = 0; mi < 4; ++mi)
            #pragma unroll
            for (int ni = 0; ni < 4; ++ni) {
                acc[mi][ni] = __builtin_amdgcn_mfma_f32_16x16x32_bf16(
                    af[mi], bw[ni], acc[mi][ni], 0, 0, 0);
                acc[mi][ni] = __builtin_amdgcn_mfma_f32_16x16x32_bf16(
                    ab[mi], bw[ni], acc[mi][ni], 0, 0, 0);
            }
    }

    #pragma unroll
    for (int mi = 0; mi < 4; ++mi)
        #pragma unroll
        for (int ni = 0; ni < 4; ++ni)
            #pragma unroll
            for (int r = 0; r < 4; ++r)
                sD[mi * 16 + lg * 4 + r][cbase + ni * 16 + l15] = acc[mi][ni][r];
    __syncthreads();

    #pragma unroll
    for (int q = 0; q < 16; ++q) {
        int f4 = q * 256 + tid;
        int cc = f4 >> 4, m4 = f4 & 15;
        size_t idx = ((size_t)(g * 256 + cc)) * 4096 + (size_t)l * 64 + m4 * 4;
        float4 xr = *(const float4*)(x + idx);
        float4 v;
        v.x = sD[m4 * 4 + 0][cc] + xr.x;
        v.y = sD[m4 * 4 + 1][cc] + xr.y;
        v.z = sD[m4 * 4 + 2][cc] + xr.z;
        v.w = sD[m4 * 4 + 3][cc] + xr.w;
        *(float4*)(out + idx) = v;
    }
}

extern "C" void kernel_launch(void* const* d_in, const int* in_sizes, int n_in,
                              void* d_out, int out_size, void* d_ws, size_t ws_size,
                              hipStream_t stream) {
    const float* x        = (const float*)d_in[0];
    const float* ln_g     = (const float*)d_in[1];
    const float* ln_b     = (const float*)d_in[2];
    const float* in_w     = (const float*)d_in[3];
    const float* conv_w   = (const float*)d_in[4];
    const float* conv_b   = (const float*)d_in[5];
    const float* xproj_w  = (const float*)d_in[6];
    const float* dtp_w    = (const float*)d_in[7];
    const float* dtp_b    = (const float*)d_in[8];
    const float* A_log    = (const float*)d_in[9];
    const float* D_f      = (const float*)d_in[10];
    const float* conv_w_b = (const float*)d_in[11];
    const float* conv_b_b = (const float*)d_in[12];
    const float* xproj_wb = (const float*)d_in[13];
    const float* dtp_w_b  = (const float*)d_in[14];
    const float* dtp_b_b  = (const float*)d_in[15];
    const float* A_b_log  = (const float*)d_in[16];
    const float* D_b      = (const float*)d_in[17];
    const float* out_w    = (const float*)d_in[18];
    float* out = (float*)d_out;

    float* ws  = (float*)d_ws;
    float* xz  = ws + OFF_XZ;
    float* xc  = ws + OFF_XC;
    float* dl  = ws + OFF_DL;
    float* bc  = ws + OFF_BC;
    unsigned short* w_bf = (unsigned short*)(ws + OFF_BC);   // free until k_cxg writes bcb
    unsigned short* yf   = (unsigned short*)(ws + OFF_YF);
    unsigned short* yb   = (unsigned short*)(ws + OFF_YB);
    unsigned short* wob  = (unsigned short*)(ws + OFF_WOB);
    unsigned short* wx   = (unsigned short*)(ws + OFF_WX);

    // 0. weight prep (re-done every launch; ws is re-poisoned)
    k_cvt_w<<<256, 256, 0, stream>>>(in_w, w_bf, 65536);
    k_cvt_w<<<128, 256, 0, stream>>>(out_w, wob, 32768);
    // 1. LN + in_proj (bf16 MFMA)
    k_ln_inproj_mfma<<<512, 256, 0, stream>>>(x, ln_g, ln_b, w_bf, xz);
    // forward branch: fused conv + projection GEMM, then scan -> yf (bf16)
    k_mk_wx<<<544, 256, 0, stream>>>(xproj_w, dtp_w, wx);
    k_cxg<<<256, 256, 0, stream>>>(xz, conv_w, conv_b, wx, dtp_b, xc, dl, bc, 0);
    k_scan<<<256, 256, 0, stream>>>(dl, xc, bc, xz, A_log, D_f, yf, 0);
    // backward branch -> yb (bf16)
    k_mk_wx<<<544, 256, 0, stream>>>(xproj_wb, dtp_w_b, wx);
    k_cxg<<<256, 256, 0, stream>>>(xz, conv_w_b, conv_b_b, wx, dtp_b_b, xc, dl, bc, 1);
    k_scan<<<256, 256, 0, stream>>>(dl, xc, bc, xz, A_b_log, D_b, yb, 1);
    // out_proj (MFMA over yf+yb) + un-shuffle + residual
    k_outproj_mfma<<<128, 256, 0, stream>>>(yf, yb, wob, x, out);
}

// Round 12
// 366.559 us; speedup vs baseline: 1.0761x; 1.0761x over previous
//
#include <hip/hip_runtime.h>

// BiPixelMambaLayer: D_MODEL=256, D_INNER=512, D_STATE=16, D_CONV=4, DT_RANK=16, PATCH=64
// x: (2, 256, 4096) fp32.  Mamba batch B'=128 (= 2*64), seq NPT=64, channels along patch axis.
//
// Workspace layout (float slots), ~85.25 MB:
//   XZ  [128][64][1024]       = 8388608
//   XC  [128][64][512]        = 4194304
//   DL  [128][64][512]        = 4194304
//   BCB [128][64][32]         = 262144   (first half doubles as in_proj W bf16 during K1)
//   YF  bf16 [128][64][512]   = 2097152 float-slots (head doubles as Wx_f before scan_f)
//   YB  bf16 [128][64][512]   = 2097152 float-slots (head doubles as Wx_b before scan_b)
//   WOB bf16 [256][512]       = 65536 float-slots

#define OFF_XZ 0
#define OFF_XC 8388608
#define OFF_DL 12582912
#define OFF_BC 16777216
#define OFF_YF 17039360
#define OFF_YB 19136512
#define OFF_WOB 21233664

typedef __attribute__((ext_vector_type(8))) short short8;
typedef __attribute__((ext_vector_type(4))) float f32x4;

__device__ __forceinline__ float siluf(float v) {
    return v / (1.f + __expf(-v));
}
__device__ __forceinline__ float softplusf(float v) {
    return (v > 20.f) ? v : log1pf(__expf(v));
}
__device__ __forceinline__ unsigned short f2bf(float f) {
    union { float f; unsigned int u; } v; v.f = f;
    unsigned int u = v.u;
    return (unsigned short)((u + 0x7FFFu + ((u >> 16) & 1u)) >> 16);
}

__device__ __forceinline__ void mk_wx_row(
    const float* __restrict__ W6, const float* __restrict__ dtw,
    unsigned short* __restrict__ Wx, int n, int c)
{
    if (n < 512) {
        float a0 = 0.f, a1 = 0.f;
        #pragma unroll
        for (int r = 0; r < 16; ++r) {
            float w = dtw[n * 16 + r];
            a0 = fmaf(w, W6[r * 512 + c], a0);
            a1 = fmaf(w, W6[r * 512 + c + 256], a1);
        }
        Wx[n * 512 + c] = f2bf(a0);
        Wx[n * 512 + c + 256] = f2bf(a1);
    } else {
        int rr = n - 496;              // W6 rows 16..47 (B then C)
        Wx[n * 512 + c] = f2bf(W6[rr * 512 + c]);
        Wx[n * 512 + c + 256] = f2bf(W6[rr * 512 + c + 256]);
    }
}

// ---------------- K0: all weight prep in ONE launch ----------------
// blocks [0,256): in_w cvt; [256,384): out_w cvt; [384,928): Wx fwd; [928,1472): Wx bwd
__global__ __launch_bounds__(256) void k_prep(
    const float* __restrict__ in_w, const float* __restrict__ out_w,
    const float* __restrict__ W6f, const float* __restrict__ dtwf,
    const float* __restrict__ W6b, const float* __restrict__ dtwb,
    unsigned short* __restrict__ w_bf, unsigned short* __restrict__ wob,
    unsigned short* __restrict__ wxf, unsigned short* __restrict__ wxb)
{
    const int bid = blockIdx.x, t = threadIdx.x;
    if (bid < 256) {
        int i = (bid * 256 + t) * 4;
        float4 v = *(const float4*)(in_w + i);
        ushort4 o;
        o.x = f2bf(v.x); o.y = f2bf(v.y); o.z = f2bf(v.z); o.w = f2bf(v.w);
        *(ushort4*)(w_bf + i) = o;
    } else if (bid < 384) {
        int i = ((bid - 256) * 256 + t) * 4;
        float4 v = *(const float4*)(out_w + i);
        ushort4 o;
        o.x = f2bf(v.x); o.y = f2bf(v.y); o.z = f2bf(v.z); o.w = f2bf(v.w);
        *(ushort4*)(wob + i) = o;
    } else if (bid < 928) {
        mk_wx_row(W6f, dtwf, wxf, bid - 384, t);
    } else {
        mk_wx_row(W6b, dtwb, wxb, bid - 928, t);
    }
}

// ---------------- K1: LayerNorm + in_proj (256 -> 1024) via bf16 MFMA ----------------
__global__ __launch_bounds__(256) void k_ln_inproj_mfma(
    const float* __restrict__ x, const float* __restrict__ g,
    const float* __restrict__ bt, const unsigned short* __restrict__ Wb,
    float* __restrict__ xz)
{
    __shared__ unsigned short sxb[64 * 256];   // 32 KB, bf16, XOR-swizzled rows of 512B
    const int bid = blockIdx.x;
    const int pg = bid >> 2, og = bid & 3;
    const int p0 = pg * 64;
    const int tid = threadIdx.x;
    const int wave = tid >> 6, lane = tid & 63;
    const int b = pg >> 6, pp = pg & 63;
    const float* xb = x + ((size_t)b * 256) * 4096 + pp;

    const int c = lane * 4;
    const float g0 = g[c + 0], g1 = g[c + 1], g2 = g[c + 2], g3 = g[c + 3];
    const float b0 = bt[c + 0], b1 = bt[c + 1], b2 = bt[c + 2], b3 = bt[c + 3];
    for (int i = 0; i < 16; ++i) {
        int m = wave * 16 + i;
        const float* xr = xb + m * 64;
        float v0 = xr[(size_t)(c + 0) * 4096];
        float v1 = xr[(size_t)(c + 1) * 4096];
        float v2 = xr[(size_t)(c + 2) * 4096];
        float v3 = xr[(size_t)(c + 3) * 4096];
        float s = v0 + v1 + v2 + v3;
        #pragma unroll
        for (int o = 32; o; o >>= 1) s += __shfl_xor(s, o);
        float mu = s * (1.f / 256.f);
        float q0 = v0 - mu, q1 = v1 - mu, q2 = v2 - mu, q3 = v3 - mu;
        float q = q0 * q0 + q1 * q1 + q2 * q2 + q3 * q3;
        #pragma unroll
        for (int o = 32; o; o >>= 1) q += __shfl_xor(q, o);
        float rs = rsqrtf(q * (1.f / 256.f) + 1e-5f);
        ushort4 pk;
        pk.x = f2bf(q0 * rs * g0 + b0);
        pk.y = f2bf(q1 * rs * g1 + b1);
        pk.z = f2bf(q2 * rs * g2 + b2);
        pk.w = f2bf(q3 * rs * g3 + b3);
        int byte = m * 512 + lane * 8;
        byte ^= (m & 7) << 4;
        *(ushort4*)((char*)sxb + byte) = pk;
    }
    __syncthreads();

    const int nbase = og * 256 + wave * 64;
    const int l15 = lane & 15, lg = lane >> 4;
    f32x4 acc[4][4];
    #pragma unroll
    for (int mi = 0; mi < 4; ++mi)
        #pragma unroll
        for (int ni = 0; ni < 4; ++ni) acc[mi][ni] = (f32x4){0.f, 0.f, 0.f, 0.f};

    const unsigned short* wrow[4];
    #pragma unroll
    for (int ni = 0; ni < 4; ++ni)
        wrow[ni] = Wb + (size_t)(nbase + ni * 16 + l15) * 256 + lg * 8;

    #pragma unroll 2
    for (int k0 = 0; k0 < 256; k0 += 32) {
        short8 a[4], bfr[4];
        #pragma unroll
        for (int mi = 0; mi < 4; ++mi) {
            int row = mi * 16 + l15;
            int byte = row * 512 + k0 * 2 + lg * 16;
            byte ^= (row & 7) << 4;
            a[mi] = *(const short8*)((const char*)sxb + byte);
        }
        #pragma unroll
        for (int ni = 0; ni < 4; ++ni)
            bfr[ni] = *(const short8*)(wrow[ni] + k0);
        #pragma unroll
        for (int mi = 0; mi < 4; ++mi)
            #pragma unroll
            for (int ni = 0; ni < 4; ++ni)
                acc[mi][ni] = __builtin_amdgcn_mfma_f32_16x16x32_bf16(
                    a[mi], bfr[ni], acc[mi][ni], 0, 0, 0);
    }

    #pragma unroll
    for (int mi = 0; mi < 4; ++mi)
        #pragma unroll
        for (int ni = 0; ni < 4; ++ni)
            #pragma unroll
            for (int r = 0; r < 4; ++r)
                xz[(size_t)(p0 + mi * 16 + lg * 4 + r) * 1024 + nbase + ni * 16 + l15] =
                    acc[mi][ni][r];
}

// ---------------- K2: fused conv+SiLU -> GEMM [16x512]@Wx^T -> delta/B/C ----------------
// Grid 512 = 128 bp x 4 M-quarters (16 positions). Block 256 = 4 waves.
// Conv once per position (thread owns 2 channels, streams 16 positions) -> 16KB LDS
// (bf16, XOR-swizzled). Waves N-split the 34 output tiles as 9/9/8/8.
__global__ __launch_bounds__(256) void k_cxg(
    const float* __restrict__ xz, const float* __restrict__ cw,
    const float* __restrict__ cb, const unsigned short* __restrict__ Wx,
    const float* __restrict__ dtb,
    float* __restrict__ xc, float* __restrict__ delta,
    float* __restrict__ bcb, int rev)
{
    __shared__ unsigned short sxb[16 * 512];   // 16 KB, rows of 1024B, XOR-swizzled
    const int blk = blockIdx.x;
    const int bp = blk >> 2, mq = blk & 3;
    const int i0 = mq << 4;
    const int tid = threadIdx.x;
    const int wave = tid >> 6, lane = tid & 63;
    const size_t xzrow = (size_t)bp * 64;

    // ---- conv + silu: thread owns channels c0, c0+1 over positions i0..i0+15 ----
    {
        const int c0 = tid * 2;
        float4 w0 = *(const float4*)&cw[c0 * 4];
        float4 w1 = *(const float4*)&cw[(c0 + 1) * 4];
        float2 bb = *(const float2*)&cb[c0];
        float2 h1 = {0.f, 0.f}, h2 = {0.f, 0.f}, h3 = {0.f, 0.f};
        if (i0 > 0) {
            h1 = *(const float2*)&xz[(xzrow + (rev ? 63 - (i0 - 1) : i0 - 1)) * 1024 + c0];
            h2 = *(const float2*)&xz[(xzrow + (rev ? 63 - (i0 - 2) : i0 - 2)) * 1024 + c0];
            h3 = *(const float2*)&xz[(xzrow + (rev ? 63 - (i0 - 3) : i0 - 3)) * 1024 + c0];
        }
        for (int p = 0; p < 16; ++p) {
            int i = i0 + p;
            int l = rev ? 63 - i : i;
            float2 cur = *(const float2*)&xz[(xzrow + l) * 1024 + c0];
            float s0 = siluf(w0.w * cur.x + w0.z * h1.x + w0.y * h2.x + w0.x * h3.x + bb.x);
            float s1 = siluf(w1.w * cur.y + w1.z * h1.y + w1.y * h2.y + w1.x * h3.y + bb.y);
            float2 sv; sv.x = s0; sv.y = s1;
            *(float2*)&xc[(xzrow + i) * 512 + c0] = sv;
            int byte = p * 1024 + c0 * 2;
            byte ^= (p & 7) << 4;
            ushort2 pk; pk.x = f2bf(s0); pk.y = f2bf(s1);
            *(ushort2*)((char*)sxb + byte) = pk;
            h3 = h2; h2 = h1; h1 = cur;
        }
    }
    __syncthreads();

    // ---- GEMM: M = 16 rows (this quarter), N tiles 9/9/8/8 per wave, K = 512 ----
    const int l15 = lane & 15, lg = lane >> 4;
    const int nt = (wave < 2) ? 9 : 8;
    const int tbase = (wave < 2) ? wave * 9 : 18 + (wave - 2) * 8;
    f32x4 acc[9];
    #pragma unroll
    for (int ni = 0; ni < 9; ++ni) acc[ni] = (f32x4){0.f, 0.f, 0.f, 0.f};
    const unsigned short* bbase = Wx + (size_t)(tbase * 16 + l15) * 512 + lg * 8;
    const int abase = l15 * 1024 + lg * 16;
    const int aswz = (l15 & 7) << 4;

    for (int k0 = 0; k0 < 512; k0 += 32) {
        short8 af = *(const short8*)((const char*)sxb + ((abase + k0 * 2) ^ aswz));
        #pragma unroll
        for (int ni = 0; ni < 9; ++ni) {
            if (ni < nt) {
                short8 bw = *(const short8*)(bbase + (size_t)ni * 8192 + k0);
                acc[ni] = __builtin_amdgcn_mfma_f32_16x16x32_bf16(af, bw, acc[ni], 0, 0, 0);
            }
        }
    }

    // ---- epilogue ----
    #pragma unroll
    for (int ni = 0; ni < 9; ++ni) {
        if (ni < nt) {
            int col = (tbase + ni) * 16 + l15;
            if (col < 512) {
                float bias = dtb[col];
                #pragma unroll
                for (int r = 0; r < 4; ++r)
                    delta[(xzrow + i0 + lg * 4 + r) * 512 + col] =
                        softplusf(acc[ni][r] + bias);
            } else {
                #pragma unroll
                for (int r = 0; r < 4; ++r)
                    bcb[(xzrow + i0 + lg * 4 + r) * 32 + (col - 512)] = acc[ni][r];
            }
        }
    }
}

// ---------------- K4: selective scan + D*u + SiLU(z) gate -> bf16 ----------------
__global__ __launch_bounds__(256) void k_scan(
    const float* __restrict__ delta, const float* __restrict__ u_,
    const float* __restrict__ bc_, const float* __restrict__ xz,
    const float* __restrict__ A_log, const float* __restrict__ Dp,
    unsigned short* __restrict__ yout, int rev)
{
    const int bid = blockIdx.x;
    const int bp  = bid >> 1;
    const int d   = ((bid & 1) << 8) + threadIdx.x;

    float a[16];
    #pragma unroll
    for (int n = 0; n < 16; ++n) a[n] = -__expf(A_log[(size_t)d * 16 + n]);
    const float Dd = Dp[d];

    float h[16];
    #pragma unroll
    for (int n = 0; n < 16; ++n) h[n] = 0.f;

    for (int l = 0; l < 64; ++l) {
        size_t base = (size_t)bp * 64 + l;
        float dl = delta[base * 512 + d];
        float uu = u_[base * 512 + d];
        float du = dl * uu;
        const float4* bc = (const float4*)(bc_ + base * 32);
        float y = 0.f;
        #pragma unroll
        for (int n4 = 0; n4 < 4; ++n4) {
            float4 Bv = bc[n4];
            float4 Cv = bc[4 + n4];
            int n = n4 * 4;
            h[n + 0] = fmaf(__expf(dl * a[n + 0]), h[n + 0], du * Bv.x); y = fmaf(h[n + 0], Cv.x, y);
            h[n + 1] = fmaf(__expf(dl * a[n + 1]), h[n + 1], du * Bv.y); y = fmaf(h[n + 1], Cv.y, y);
            h[n + 2] = fmaf(__expf(dl * a[n + 2]), h[n + 2], du * Bv.z); y = fmaf(h[n + 2], Cv.z, y);
            h[n + 3] = fmaf(__expf(dl * a[n + 3]), h[n + 3], du * Bv.w); y = fmaf(h[n + 3], Cv.w, y);
        }
        y = fmaf(Dd, uu, y);
        int lo = rev ? 63 - l : l;
        float zv = xz[((size_t)bp * 64 + lo) * 1024 + 512 + d];
        yout[((size_t)bp * 64 + lo) * 512 + d] = f2bf(y * siluf(zv));
    }
}

// ---------------- K5: out_proj (512 -> 256) via bf16 MFMA + un-shuffle + residual -----
__global__ __launch_bounds__(256) void k_outproj_mfma(
    const unsigned short* __restrict__ yf, const unsigned short* __restrict__ yb,
    const unsigned short* __restrict__ wob, const float* __restrict__ x,
    float* __restrict__ out)
{
    __shared__ float sD[64][257];
    const int blk = blockIdx.x;
    const int g = blk >> 6, l = blk & 63;
    const int tid = threadIdx.x;
    const int wave = tid >> 6, lane = tid & 63;
    const int l15 = lane & 15, lg = lane >> 4;
    const int cbase = wave * 64;

    f32x4 acc[4][4];
    #pragma unroll
    for (int mi = 0; mi < 4; ++mi)
        #pragma unroll
        for (int ni = 0; ni < 4; ++ni) acc[mi][ni] = (f32x4){0.f, 0.f, 0.f, 0.f};

    const unsigned short* arf[4];
    const unsigned short* arb[4];
    #pragma unroll
    for (int mi = 0; mi < 4; ++mi) {
        size_t idx = (((size_t)(g * 64 + mi * 16 + l15)) * 64 + l) * 512 + lg * 8;
        arf[mi] = yf + idx;
        arb[mi] = yb + idx;
    }
    const unsigned short* brow[4];
    #pragma unroll
    for (int ni = 0; ni < 4; ++ni)
        brow[ni] = wob + (size_t)(cbase + ni * 16 + l15) * 512 + lg * 8;

    #pragma unroll 2
    for (int k0 = 0; k0 < 512; k0 += 32) {
        short8 bw[4], af[4], ab[4];
        #pragma unroll
        for (int ni = 0; ni < 4; ++ni) bw[ni] = *(const short8*)(brow[ni] + k0);
        #pragma unroll
        for (int mi = 0; mi < 4; ++mi) {
            af[mi] = *(const short8*)(arf[mi] + k0);
            ab[mi] = *(const short8*)(arb[mi] + k0);
        }
        #pragma unroll
        for (int mi = 0; mi < 4; ++mi)
            #pragma unroll
            for (int ni = 0; ni < 4; ++ni) {
                acc[mi][ni] = __builtin_amdgcn_mfma_f32_16x16x32_bf16(
                    af[mi], bw[ni], acc[mi][ni], 0, 0, 0);
                acc[mi][ni] = __builtin_amdgcn_mfma_f32_16x16x32_bf16(
                    ab[mi], bw[ni], acc[mi][ni], 0, 0, 0);
            }
    }

    #pragma unroll
    for (int mi = 0; mi < 4; ++mi)
        #pragma unroll
        for (int ni = 0; ni < 4; ++ni)
            #pragma unroll
            for (int r = 0; r < 4; ++r)
                sD[mi * 16 + lg * 4 + r][cbase + ni * 16 + l15] = acc[mi][ni][r];
    __syncthreads();

    #pragma unroll
    for (int q = 0; q < 16; ++q) {
        int f4 = q * 256 + tid;
        int cc = f4 >> 4, m4 = f4 & 15;
        size_t idx = ((size_t)(g * 256 + cc)) * 4096 + (size_t)l * 64 + m4 * 4;
        float4 xr = *(const float4*)(x + idx);
        float4 v;
        v.x = sD[m4 * 4 + 0][cc] + xr.x;
        v.y = sD[m4 * 4 + 1][cc] + xr.y;
        v.z = sD[m4 * 4 + 2][cc] + xr.z;
        v.w = sD[m4 * 4 + 3][cc] + xr.w;
        *(float4*)(out + idx) = v;
    }
}

extern "C" void kernel_launch(void* const* d_in, const int* in_sizes, int n_in,
                              void* d_out, int out_size, void* d_ws, size_t ws_size,
                              hipStream_t stream) {
    const float* x        = (const float*)d_in[0];
    const float* ln_g     = (const float*)d_in[1];
    const float* ln_b     = (const float*)d_in[2];
    const float* in_w     = (const float*)d_in[3];
    const float* conv_w   = (const float*)d_in[4];
    const float* conv_b   = (const float*)d_in[5];
    const float* xproj_w  = (const float*)d_in[6];
    const float* dtp_w    = (const float*)d_in[7];
    const float* dtp_b    = (const float*)d_in[8];
    const float* A_log    = (const float*)d_in[9];
    const float* D_f      = (const float*)d_in[10];
    const float* conv_w_b = (const float*)d_in[11];
    const float* conv_b_b = (const float*)d_in[12];
    const float* xproj_wb = (const float*)d_in[13];
    const float* dtp_w_b  = (const float*)d_in[14];
    const float* dtp_b_b  = (const float*)d_in[15];
    const float* A_b_log  = (const float*)d_in[16];
    const float* D_b      = (const float*)d_in[17];
    const float* out_w    = (const float*)d_in[18];
    float* out = (float*)d_out;

    float* ws  = (float*)d_ws;
    float* xz  = ws + OFF_XZ;
    float* xc  = ws + OFF_XC;
    float* dl  = ws + OFF_DL;
    float* bc  = ws + OFF_BC;
    unsigned short* w_bf = (unsigned short*)(ws + OFF_BC);   // free until k_cxg writes bcb
    unsigned short* yf   = (unsigned short*)(ws + OFF_YF);
    unsigned short* yb   = (unsigned short*)(ws + OFF_YB);
    unsigned short* wob  = (unsigned short*)(ws + OFF_WOB);
    // Wx buffers live at the HEAD of YF/YB: consumed by k_cxg, then overwritten by k_scan.
    unsigned short* wxf  = yf;
    unsigned short* wxb  = yb;

    // 0. all weight prep in one launch
    k_prep<<<1472, 256, 0, stream>>>(in_w, out_w, xproj_w, dtp_w, xproj_wb, dtp_w_b,
                                     w_bf, wob, wxf, wxb);
    // 1. LN + in_proj (bf16 MFMA)
    k_ln_inproj_mfma<<<512, 256, 0, stream>>>(x, ln_g, ln_b, w_bf, xz);
    // forward branch: fused conv + projection GEMM, then scan -> yf (bf16)
    k_cxg<<<512, 256, 0, stream>>>(xz, conv_w, conv_b, wxf, dtp_b, xc, dl, bc, 0);
    k_scan<<<256, 256, 0, stream>>>(dl, xc, bc, xz, A_log, D_f, yf, 0);
    // backward branch -> yb (bf16)
    k_cxg<<<512, 256, 0, stream>>>(xz, conv_w_b, conv_b_b, wxb, dtp_b_b, xc, dl, bc, 1);
    k_scan<<<256, 256, 0, stream>>>(dl, xc, bc, xz, A_b_log, D_b, yb, 1);
    // out_proj (MFMA over yf+yb) + un-shuffle + residual
    k_outproj_mfma<<<128, 256, 0, stream>>>(yf, yb, wob, x, out);
}

// Round 15
// 323.277 us; speedup vs baseline: 1.2202x; 1.1339x over previous
//
#include <hip/hip_runtime.h>

// BiPixelMambaLayer: D_MODEL=256, D_INNER=512, D_STATE=16, D_CONV=4, DT_RANK=16, PATCH=64
// x: (2, 256, 4096) fp32.  Mamba batch B'=128 (= 2*64), seq NPT=64, channels along patch axis.
//
// Workspace (float slots), ~69.5 MB. bf16 intermediates; separate fwd/bwd buffers so both
// branches run concurrently in one launch.
//   XZ  bf16 [128][64][1024] = 4194304 slots
//   XCF/XCB bf16 [128][64][512] = 2097152 each
//   DLF/DLB bf16 [128][64][512] = 2097152 each
//   BCF/BCB fp32 [128][64][32]  = 262144 each  (BCF head doubles as in_proj W bf16)
//   YF/YB bf16 [128][64][512]   = 2097152 each (heads double as Wx_f / Wx_b)
//   WOB bf16 [256][512]         = 65536

#define OFF_XZ   0
#define OFF_XCF  4194304
#define OFF_XCB  6291456
#define OFF_DLF  8388608
#define OFF_DLB  10485760
#define OFF_BCF  12582912
#define OFF_BCB  12845056
#define OFF_YF   13107200
#define OFF_YB   15204352
#define OFF_WOB  17301504

typedef __attribute__((ext_vector_type(8))) short short8;
typedef __attribute__((ext_vector_type(4))) float f32x4;

__device__ __forceinline__ float siluf(float v) {
    return v / (1.f + __expf(-v));
}
__device__ __forceinline__ float softplusf(float v) {
    return (v > 20.f) ? v : log1pf(__expf(v));
}
__device__ __forceinline__ unsigned short f2bf(float f) {
    union { float f; unsigned int u; } v; v.f = f;
    unsigned int u = v.u;
    return (unsigned short)((u + 0x7FFFu + ((u >> 16) & 1u)) >> 16);
}
__device__ __forceinline__ float bf2f(unsigned short u) {
    union { unsigned int u; float f; } v; v.u = ((unsigned int)u) << 16;
    return v.f;
}
__device__ __forceinline__ float4 bf4(ushort4 u) {
    float4 f; f.x = bf2f(u.x); f.y = bf2f(u.y); f.z = bf2f(u.z); f.w = bf2f(u.w);
    return f;
}

__device__ __forceinline__ void mk_wx_row(
    const float* __restrict__ W6, const float* __restrict__ dtw,
    unsigned short* __restrict__ Wx, int n, int c)
{
    if (n < 512) {
        float a0 = 0.f, a1 = 0.f;
        #pragma unroll
        for (int r = 0; r < 16; ++r) {
            float w = dtw[n * 16 + r];
            a0 = fmaf(w, W6[r * 512 + c], a0);
            a1 = fmaf(w, W6[r * 512 + c + 256], a1);
        }
        Wx[n * 512 + c] = f2bf(a0);
        Wx[n * 512 + c + 256] = f2bf(a1);
    } else {
        int rr = n - 496;              // W6 rows 16..47 (B then C)
        Wx[n * 512 + c] = f2bf(W6[rr * 512 + c]);
        Wx[n * 512 + c + 256] = f2bf(W6[rr * 512 + c + 256]);
    }
}

// ---------------- K0: all weight prep in ONE launch ----------------
// blocks [0,256): in_w cvt; [256,384): out_w cvt; [384,928): Wx fwd; [928,1472): Wx bwd
__global__ __launch_bounds__(256) void k_prep(
    const float* __restrict__ in_w, const float* __restrict__ out_w,
    const float* __restrict__ W6f, const float* __restrict__ dtwf,
    const float* __restrict__ W6b, const float* __restrict__ dtwb,
    unsigned short* __restrict__ w_bf, unsigned short* __restrict__ wob,
    unsigned short* __restrict__ wxf, unsigned short* __restrict__ wxb)
{
    const int bid = blockIdx.x, t = threadIdx.x;
    if (bid < 256) {
        int i = (bid * 256 + t) * 4;
        float4 v = *(const float4*)(in_w + i);
        ushort4 o;
        o.x = f2bf(v.x); o.y = f2bf(v.y); o.z = f2bf(v.z); o.w = f2bf(v.w);
        *(ushort4*)(w_bf + i) = o;
    } else if (bid < 384) {
        int i = ((bid - 256) * 256 + t) * 4;
        float4 v = *(const float4*)(out_w + i);
        ushort4 o;
        o.x = f2bf(v.x); o.y = f2bf(v.y); o.z = f2bf(v.z); o.w = f2bf(v.w);
        *(ushort4*)(wob + i) = o;
    } else if (bid < 928) {
        mk_wx_row(W6f, dtwf, wxf, bid - 384, t);
    } else {
        mk_wx_row(W6b, dtwb, wxb, bid - 928, t);
    }
}

// ---------------- K1: LayerNorm + in_proj (256 -> 1024) via bf16 MFMA, bf16 out -------
__global__ __launch_bounds__(256) void k_ln_inproj_mfma(
    const float* __restrict__ x, const float* __restrict__ g,
    const float* __restrict__ bt, const unsigned short* __restrict__ Wb,
    unsigned short* __restrict__ xz)
{
    __shared__ unsigned short sxb[64 * 256];   // 32 KB, bf16, XOR-swizzled rows of 512B
    const int bid = blockIdx.x;
    const int pg = bid >> 2, og = bid & 3;
    const int p0 = pg * 64;
    const int tid = threadIdx.x;
    const int wave = tid >> 6, lane = tid & 63;
    const int b = pg >> 6, pp = pg & 63;
    const float* xb = x + ((size_t)b * 256) * 4096 + pp;

    const int c = lane * 4;
    const float g0 = g[c + 0], g1 = g[c + 1], g2 = g[c + 2], g3 = g[c + 3];
    const float b0 = bt[c + 0], b1 = bt[c + 1], b2 = bt[c + 2], b3 = bt[c + 3];
    for (int i = 0; i < 16; ++i) {
        int m = wave * 16 + i;
        const float* xr = xb + m * 64;
        float v0 = xr[(size_t)(c + 0) * 4096];
        float v1 = xr[(size_t)(c + 1) * 4096];
        float v2 = xr[(size_t)(c + 2) * 4096];
        float v3 = xr[(size_t)(c + 3) * 4096];
        float s = v0 + v1 + v2 + v3;
        #pragma unroll
        for (int o = 32; o; o >>= 1) s += __shfl_xor(s, o);
        float mu = s * (1.f / 256.f);
        float q0 = v0 - mu, q1 = v1 - mu, q2 = v2 - mu, q3 = v3 - mu;
        float q = q0 * q0 + q1 * q1 + q2 * q2 + q3 * q3;
        #pragma unroll
        for (int o = 32; o; o >>= 1) q += __shfl_xor(q, o);
        float rs = rsqrtf(q * (1.f / 256.f) + 1e-5f);
        ushort4 pk;
        pk.x = f2bf(q0 * rs * g0 + b0);
        pk.y = f2bf(q1 * rs * g1 + b1);
        pk.z = f2bf(q2 * rs * g2 + b2);
        pk.w = f2bf(q3 * rs * g3 + b3);
        int byte = m * 512 + lane * 8;
        byte ^= (m & 7) << 4;
        *(ushort4*)((char*)sxb + byte) = pk;
    }
    __syncthreads();

    const int nbase = og * 256 + wave * 64;
    const int l15 = lane & 15, lg = lane >> 4;
    f32x4 acc[4][4];
    #pragma unroll
    for (int mi = 0; mi < 4; ++mi)
        #pragma unroll
        for (int ni = 0; ni < 4; ++ni) acc[mi][ni] = (f32x4){0.f, 0.f, 0.f, 0.f};

    const unsigned short* wrow[4];
    #pragma unroll
    for (int ni = 0; ni < 4; ++ni)
        wrow[ni] = Wb + (size_t)(nbase + ni * 16 + l15) * 256 + lg * 8;

    #pragma unroll 2
    for (int k0 = 0; k0 < 256; k0 += 32) {
        short8 a[4], bfr[4];
        #pragma unroll
        for (int mi = 0; mi < 4; ++mi) {
            int row = mi * 16 + l15;
            int byte = row * 512 + k0 * 2 + lg * 16;
            byte ^= (row & 7) << 4;
            a[mi] = *(const short8*)((const char*)sxb + byte);
        }
        #pragma unroll
        for (int ni = 0; ni < 4; ++ni)
            bfr[ni] = *(const short8*)(wrow[ni] + k0);
        #pragma unroll
        for (int mi = 0; mi < 4; ++mi)
            #pragma unroll
            for (int ni = 0; ni < 4; ++ni)
                acc[mi][ni] = __builtin_amdgcn_mfma_f32_16x16x32_bf16(
                    a[mi], bfr[ni], acc[mi][ni], 0, 0, 0);
    }

    #pragma unroll
    for (int mi = 0; mi < 4; ++mi)
        #pragma unroll
        for (int ni = 0; ni < 4; ++ni)
            #pragma unroll
            for (int r = 0; r < 4; ++r)
                xz[(size_t)(p0 + mi * 16 + lg * 4 + r) * 1024 + nbase + ni * 16 + l15] =
                    f2bf(acc[mi][ni][r]);
}

// ---------------- K2: BOTH branches: conv+SiLU -> GEMM [64x512]@Wx^T -> delta/B/C ------
// Grid 512 = 2 branches x 128 bp x 2 og (column halves of 272). Block 256 = 4 waves.
// R10-proven shape: wave convs 16 positions (all 512 ch) into 64KB swizzled bf16 LDS,
// then GEMM M=16(own rows) x N=272(og half), 17 tiles. 2 blocks/CU co-resident.
__global__ __launch_bounds__(256) void k_cxg2(
    const unsigned short* __restrict__ xz,
    const float* __restrict__ cwf, const float* __restrict__ cbf,
    const unsigned short* __restrict__ wxf, const float* __restrict__ dtbf,
    const float* __restrict__ cwb, const float* __restrict__ cbb,
    const unsigned short* __restrict__ wxb, const float* __restrict__ dtbb,
    unsigned short* __restrict__ xcf, unsigned short* __restrict__ dlf,
    float* __restrict__ bcf,
    unsigned short* __restrict__ xcb, unsigned short* __restrict__ dlb,
    float* __restrict__ bcb_)
{
    __shared__ unsigned short sxb[64 * 512];   // 64 KB, rows of 1024B, XOR-swizzled
    const int bid = blockIdx.x;
    const int branch = bid >> 8;
    const int rr = bid & 255;
    const int bp = rr >> 1, og = rr & 1;
    const int rev = branch;
    const float* cw = branch ? cwb : cwf;
    const float* cb = branch ? cbb : cbf;
    const unsigned short* Wx = branch ? wxb : wxf;
    const float* dtb = branch ? dtbb : dtbf;
    unsigned short* xc = branch ? xcb : xcf;
    unsigned short* delta = branch ? dlb : dlf;
    float* bcb = branch ? bcb_ : bcf;

    const int tid = threadIdx.x;
    const int wave = tid >> 6, lane = tid & 63;
    const size_t xzrow = (size_t)bp * 64;
    const int m0 = wave * 16;

    // ---- conv + silu: wave owns positions m0..m0+15; lane owns channels da..+3, db..+3 --
    {
        const int da = lane * 4, db = 256 + lane * 4;
        float4 wa0 = *(const float4*)&cw[(da + 0) * 4];
        float4 wa1 = *(const float4*)&cw[(da + 1) * 4];
        float4 wa2 = *(const float4*)&cw[(da + 2) * 4];
        float4 wa3 = *(const float4*)&cw[(da + 3) * 4];
        float4 wb0 = *(const float4*)&cw[(db + 0) * 4];
        float4 wb1 = *(const float4*)&cw[(db + 1) * 4];
        float4 wb2 = *(const float4*)&cw[(db + 2) * 4];
        float4 wb3 = *(const float4*)&cw[(db + 3) * 4];
        float4 ba = *(const float4*)&cb[da];
        float4 bb = *(const float4*)&cb[db];

        float4 a1 = {0,0,0,0}, a2 = {0,0,0,0}, a3 = {0,0,0,0};
        float4 c1 = {0,0,0,0}, c2 = {0,0,0,0}, c3 = {0,0,0,0};
        if (m0 > 0) {
            int i1 = m0 - 1, i2 = m0 - 2, i3 = m0 - 3;
            int l1 = rev ? 63 - i1 : i1, l2 = rev ? 63 - i2 : i2, l3 = rev ? 63 - i3 : i3;
            a1 = bf4(*(const ushort4*)&xz[(xzrow + l1) * 1024 + da]);
            a2 = bf4(*(const ushort4*)&xz[(xzrow + l2) * 1024 + da]);
            a3 = bf4(*(const ushort4*)&xz[(xzrow + l3) * 1024 + da]);
            c1 = bf4(*(const ushort4*)&xz[(xzrow + l1) * 1024 + db]);
            c2 = bf4(*(const ushort4*)&xz[(xzrow + l2) * 1024 + db]);
            c3 = bf4(*(const ushort4*)&xz[(xzrow + l3) * 1024 + db]);
        }
        for (int p = 0; p < 16; ++p) {
            int i = m0 + p;
            int l = rev ? 63 - i : i;
            float4 cura = bf4(*(const ushort4*)&xz[(xzrow + l) * 1024 + da]);
            float4 curb = bf4(*(const ushort4*)&xz[(xzrow + l) * 1024 + db]);
            ushort4 pa, pb;
            pa.x = f2bf(siluf(wa0.w * cura.x + wa0.z * a1.x + wa0.y * a2.x + wa0.x * a3.x + ba.x));
            pa.y = f2bf(siluf(wa1.w * cura.y + wa1.z * a1.y + wa1.y * a2.y + wa1.x * a3.y + ba.y));
            pa.z = f2bf(siluf(wa2.w * cura.z + wa2.z * a1.z + wa2.y * a2.z + wa2.x * a3.z + ba.z));
            pa.w = f2bf(siluf(wa3.w * cura.w + wa3.z * a1.w + wa3.y * a2.w + wa3.x * a3.w + ba.w));
            pb.x = f2bf(siluf(wb0.w * curb.x + wb0.z * c1.x + wb0.y * c2.x + wb0.x * c3.x + bb.x));
            pb.y = f2bf(siluf(wb1.w * curb.y + wb1.z * c1.y + wb1.y * c2.y + wb1.x * c3.y + bb.y));
            pb.z = f2bf(siluf(wb2.w * curb.z + wb2.z * c1.z + wb2.y * c2.z + wb2.x * c3.z + bb.z));
            pb.w = f2bf(siluf(wb3.w * curb.w + wb3.z * c1.w + wb3.y * c2.w + wb3.x * c3.w + bb.w));
            if (og == 0) {
                *(ushort4*)&xc[(xzrow + i) * 512 + da] = pa;
                *(ushort4*)&xc[(xzrow + i) * 512 + db] = pb;
            }
            int bytea = i * 1024 + da * 2; bytea ^= (i & 7) << 4;
            int byteb = i * 1024 + db * 2; byteb ^= (i & 7) << 4;
            *(ushort4*)((char*)sxb + bytea) = pa;
            *(ushort4*)((char*)sxb + byteb) = pb;
            a3 = a2; a2 = a1; a1 = cura;
            c3 = c2; c2 = c1; c1 = curb;
        }
    }
    __syncthreads();

    // ---- GEMM: wave = M16 (own rows) x N272 (og half, 17 tiles), K = 512 ----
    const int l15 = lane & 15, lg = lane >> 4;
    f32x4 acc[17];
    #pragma unroll
    for (int ni = 0; ni < 17; ++ni) acc[ni] = (f32x4){0.f, 0.f, 0.f, 0.f};
    const unsigned short* bbase = Wx + (size_t)(og * 272 + l15) * 512 + lg * 8;
    const int arow = m0 + l15;
    const int abase = arow * 1024 + lg * 16;
    const int aswz = (arow & 7) << 4;

    for (int k0 = 0; k0 < 512; k0 += 32) {
        short8 af = *(const short8*)((const char*)sxb + ((abase + k0 * 2) ^ aswz));
        #pragma unroll
        for (int ni = 0; ni < 17; ++ni) {
            short8 bw = *(const short8*)(bbase + (size_t)ni * 8192 + k0);
            acc[ni] = __builtin_amdgcn_mfma_f32_16x16x32_bf16(af, bw, acc[ni], 0, 0, 0);
        }
    }

    // ---- epilogue: softplus->delta (bf16) for cols<512, raw->bc (fp32) else ----
    #pragma unroll
    for (int ni = 0; ni < 17; ++ni) {
        int col = og * 272 + ni * 16 + l15;
        if (col < 512) {
            float bias = dtb[col];
            #pragma unroll
            for (int r = 0; r < 4; ++r) {
                int pos = m0 + lg * 4 + r;
                delta[(xzrow + pos) * 512 + col] = f2bf(softplusf(acc[ni][r] + bias));
            }
        } else {
            #pragma unroll
            for (int r = 0; r < 4; ++r) {
                int pos = m0 + lg * 4 + r;
                bcb[(xzrow + pos) * 32 + (col - 512)] = acc[ni][r];
            }
        }
    }
}

// ---------------- K4: BOTH scans: selective scan + D*u + SiLU(z) gate -> bf16 ----------
// Grid 512 = 2 branches x 128 bp x 2 d-halves.
__global__ __launch_bounds__(256) void k_scan2(
    const unsigned short* __restrict__ dlf, const unsigned short* __restrict__ xcf,
    const float* __restrict__ bcf,
    const unsigned short* __restrict__ dlb, const unsigned short* __restrict__ xcb,
    const float* __restrict__ bcb_,
    const unsigned short* __restrict__ xz,
    const float* __restrict__ A_logf, const float* __restrict__ Dpf,
    const float* __restrict__ A_logb, const float* __restrict__ Dpb,
    unsigned short* __restrict__ yf, unsigned short* __restrict__ yb)
{
    const int bid = blockIdx.x;
    const int branch = bid >> 8;
    const int rr = bid & 255;
    const int bp  = rr >> 1;
    const int d   = ((rr & 1) << 8) + threadIdx.x;
    const unsigned short* delta = branch ? dlb : dlf;
    const unsigned short* u_ = branch ? xcb : xcf;
    const float* bc_ = branch ? bcb_ : bcf;
    const float* A_log = branch ? A_logb : A_logf;
    const float* Dp = branch ? Dpb : Dpf;
    unsigned short* yout = branch ? yb : yf;
    const int rev = branch;

    float a[16];
    #pragma unroll
    for (int n = 0; n < 16; ++n) a[n] = -__expf(A_log[(size_t)d * 16 + n]);
    const float Dd = Dp[d];

    float h[16];
    #pragma unroll
    for (int n = 0; n < 16; ++n) h[n] = 0.f;

    for (int l = 0; l < 64; ++l) {
        size_t base = (size_t)bp * 64 + l;
        float dl = bf2f(delta[base * 512 + d]);
        float uu = bf2f(u_[base * 512 + d]);
        float du = dl * uu;
        const float4* bc = (const float4*)(bc_ + base * 32);
        float y = 0.f;
        #pragma unroll
        for (int n4 = 0; n4 < 4; ++n4) {
            float4 Bv = bc[n4];
            float4 Cv = bc[4 + n4];
            int n = n4 * 4;
            h[n + 0] = fmaf(__expf(dl * a[n + 0]), h[n + 0], du * Bv.x); y = fmaf(h[n + 0], Cv.x, y);
            h[n + 1] = fmaf(__expf(dl * a[n + 1]), h[n + 1], du * Bv.y); y = fmaf(h[n + 1], Cv.y, y);
            h[n + 2] = fmaf(__expf(dl * a[n + 2]), h[n + 2], du * Bv.z); y = fmaf(h[n + 2], Cv.z, y);
            h[n + 3] = fmaf(__expf(dl * a[n + 3]), h[n + 3], du * Bv.w); y = fmaf(h[n + 3], Cv.w, y);
        }
        y = fmaf(Dd, uu, y);
        int lo = rev ? 63 - l : l;
        float zv = bf2f(xz[((size_t)bp * 64 + lo) * 1024 + 512 + d]);
        yout[((size_t)bp * 64 + lo) * 512 + d] = f2bf(y * siluf(zv));
    }
}

// ---------------- K5: out_proj (512 -> 256) via bf16 MFMA + un-shuffle + residual -----
__global__ __launch_bounds__(256) void k_outproj_mfma(
    const unsigned short* __restrict__ yf, const unsigned short* __restrict__ yb,
    const unsigned short* __restrict__ wob, const float* __restrict__ x,
    float* __restrict__ out)
{
    __shared__ float sD[64][257];
    const int blk = blockIdx.x;
    const int g = blk >> 6, l = blk & 63;
    const int tid = threadIdx.x;
    const int wave = tid >> 6, lane = tid & 63;
    const int l15 = lane & 15, lg = lane >> 4;
    const int cbase = wave * 64;

    f32x4 acc[4][4];
    #pragma unroll
    for (int mi = 0; mi < 4; ++mi)
        #pragma unroll
        for (int ni = 0; ni < 4; ++ni) acc[mi][ni] = (f32x4){0.f, 0.f, 0.f, 0.f};

    const unsigned short* arf[4];
    const unsigned short* arb[4];
    #pragma unroll
    for (int mi = 0; mi < 4; ++mi) {
        size_t idx = (((size_t)(g * 64 + mi * 16 + l15)) * 64 + l) * 512 + lg * 8;
        arf[mi] = yf + idx;
        arb[mi] = yb + idx;
    }
    const unsigned short* brow[4];
    #pragma unroll
    for (int ni = 0; ni < 4; ++ni)
        brow[ni] = wob + (size_t)(cbase + ni * 16 + l15) * 512 + lg * 8;

    #pragma unroll 2
    for (int k0 = 0; k0 < 512; k0 += 32) {
        short8 bw[4], af[4], ab[4];
        #pragma unroll
        for (int ni = 0; ni < 4; ++ni) bw[ni] = *(const short8*)(brow[ni] + k0);
        #pragma unroll
        for (int mi = 0; mi < 4; ++mi) {
            af[mi] = *(const short8*)(arf[mi] + k0);
            ab[mi] = *(const short8*)(arb[mi] + k0);
        }
        #pragma unroll
        for (int mi = 0; mi < 4; ++mi)
            #pragma unroll
            for (int ni = 0; ni < 4; ++ni) {
                acc[mi][ni] = __builtin_amdgcn_mfma_f32_16x16x32_bf16(
                    af[mi], bw[ni], acc[mi][ni], 0, 0, 0);
                acc[mi][ni] = __builtin_amdgcn_mfma_f32_16x16x32_bf16(
                    ab[mi], bw[ni], acc[mi][ni], 0, 0, 0);
            }
    }

    #pragma unroll
    for (int mi = 0; mi < 4; ++mi)
        #pragma unroll
        for (int ni = 0; ni < 4; ++ni)
            #pragma unroll
            for (int r = 0; r < 4; ++r)
                sD[mi * 16 + lg * 4 + r][cbase + ni * 16 + l15] = acc[mi][ni][r];
    __syncthreads();

    #pragma unroll
    for (int q = 0; q < 16; ++q) {
        int f4 = q * 256 + tid;
        int cc = f4 >> 4, m4 = f4 & 15;
        size_t idx = ((size_t)(g * 256 + cc)) * 4096 + (size_t)l * 64 + m4 * 4;
        float4 xr = *(const float4*)(x + idx);
        float4 v;
        v.x = sD[m4 * 4 + 0][cc] + xr.x;
        v.y = sD[m4 * 4 + 1][cc] + xr.y;
        v.z = sD[m4 * 4 + 2][cc] + xr.z;
        v.w = sD[m4 * 4 + 3][cc] + xr.w;
        *(float4*)(out + idx) = v;
    }
}

extern "C" void kernel_launch(void* const* d_in, const int* in_sizes, int n_in,
                              void* d_out, int out_size, void* d_ws, size_t ws_size,
                              hipStream_t stream) {
    const float* x        = (const float*)d_in[0];
    const float* ln_g     = (const float*)d_in[1];
    const float* ln_b     = (const float*)d_in[2];
    const float* in_w     = (const float*)d_in[3];
    const float* conv_w   = (const float*)d_in[4];
    const float* conv_b   = (const float*)d_in[5];
    const float* xproj_w  = (const float*)d_in[6];
    const float* dtp_w    = (const float*)d_in[7];
    const float* dtp_b    = (const float*)d_in[8];
    const float* A_log    = (const float*)d_in[9];
    const float* D_f      = (const float*)d_in[10];
    const float* conv_w_b = (const float*)d_in[11];
    const float* conv_b_b = (const float*)d_in[12];
    const float* xproj_wb = (const float*)d_in[13];
    const float* dtp_w_b  = (const float*)d_in[14];
    const float* dtp_b_b  = (const float*)d_in[15];
    const float* A_b_log  = (const float*)d_in[16];
    const float* D_b      = (const float*)d_in[17];
    const float* out_w    = (const float*)d_in[18];
    float* out = (float*)d_out;

    float* ws  = (float*)d_ws;
    unsigned short* xzb = (unsigned short*)(ws + OFF_XZ);
    unsigned short* xcf = (unsigned short*)(ws + OFF_XCF);
    unsigned short* xcb = (unsigned short*)(ws + OFF_XCB);
    unsigned short* dlf = (unsigned short*)(ws + OFF_DLF);
    unsigned short* dlb = (unsigned short*)(ws + OFF_DLB);
    float* bcf = ws + OFF_BCF;
    float* bcb = ws + OFF_BCB;
    unsigned short* w_bf = (unsigned short*)(ws + OFF_BCF);  // dead after K1; bcf overwrites
    unsigned short* yf  = (unsigned short*)(ws + OFF_YF);
    unsigned short* yb  = (unsigned short*)(ws + OFF_YB);
    unsigned short* wob = (unsigned short*)(ws + OFF_WOB);
    unsigned short* wxf = yf;   // heads of YF/YB; dead after k_cxg2, scan overwrites
    unsigned short* wxb = yb;

    // 0. all weight prep in one launch
    k_prep<<<1472, 256, 0, stream>>>(in_w, out_w, xproj_w, dtp_w, xproj_wb, dtp_w_b,
                                     w_bf, wob, wxf, wxb);
    // 1. LN + in_proj (bf16 MFMA, bf16 xz out)
    k_ln_inproj_mfma<<<512, 256, 0, stream>>>(x, ln_g, ln_b, w_bf, xzb);
    // 2. both branches: conv + projection GEMM (concurrent, 2 blocks/CU)
    k_cxg2<<<512, 256, 0, stream>>>(xzb, conv_w, conv_b, wxf, dtp_b,
                                    conv_w_b, conv_b_b, wxb, dtp_b_b,
                                    xcf, dlf, bcf, xcb, dlb, bcb);
    // 3. both scans (concurrent)
    k_scan2<<<512, 256, 0, stream>>>(dlf, xcf, bcf, dlb, xcb, bcb, xzb,
                                     A_log, D_f, A_b_log, D_b, yf, yb);
    // 4. out_proj (MFMA over yf+yb) + un-shuffle + residual
    k_outproj_mfma<<<128, 256, 0, stream>>>(yf, yb, wob, x, out);
}